// Round 13
// baseline (260.271 us; speedup 1.0000x reference)
//
#include <hip/hip_runtime.h>
#include <cstddef>

#define Bn 128
#define Pn 8732
#define Cn 21
#define On 16

__device__ __forceinline__ void argmax_combine(float& v, int& p, float v2, int p2) {
  if (v2 > v || (v2 == v && p2 < p)) { v = v2; p = p2; }
}

__device__ __forceinline__ float sl1_enc(float4 lv, float4 d,
                                         float t0, float t1, float t2, float t3) {
  float g0 = ((t0 + t2) * 0.5f - d.x) / (0.1f * d.z);
  float g1 = ((t1 + t3) * 0.5f - d.y) / (0.1f * d.w);
  float g2 = __logf((t2 - t0) / d.z) / 0.2f;
  float g3 = __logf((t3 - t1) / d.w) / 0.2f;
  float r = 0.f, a;
  a = fabsf(lv.x - g0); r += (a < 1.f) ? 0.5f * a * a : a - 0.5f;
  a = fabsf(lv.y - g1); r += (a < 1.f) ? 0.5f * a * a : a - 0.5f;
  a = fabsf(lv.z - g2); r += (a < 1.f) ? 0.5f * a * a : a - 0.5f;
  a = fabsf(lv.w - g3); r += (a < 1.f) ? 0.5f * a * a : a - 0.5f;
  return r;
}

// LDS: stream staging (92 KB, 16 waves) and reduce scratch (~20 KB) are
// lifetime-disjoint (barrier + counter handoff between phases) -> union.
// 92 KB -> 1 block/CU -> 16 waves/CU, same occupancy as the R2 structure.
union SmemU {
  struct {
    float4 row4[16][336];          // per-wave conf staging
    float  tt[16][On * 5];
    float  ar[16][On];
  } st;
  struct {
    unsigned hist[256 * 16];       // [bin][wave]
    unsigned col[256];
    unsigned cand[64];
    unsigned bm[273];              // prior bitmap
    float    t[On * 5];
    int      bp[On];
    float    redf[2][16];
    int      redi[16];
  } rd;
};

// ---------------------------------------------------------------------------
// Fused kernel: 256 blocks x 1024 thr. Block k streams image b=k>>1 with
// chunk-groups (k&1)*16+wb (exact R2/R11 per-wave stream body, 57.6us).
// Handoff: last-arriving block of each image (atomicAdd done[b]) runs the
// FULL-WIDTH 1024-thread R9 reduce for that image (R6 lesson: 256-thr reduce
// was the 300us tail). Finalize: 128th reducer (done2) gathers res -> out.
// Spin-free everywhere -> no co-residency assumptions, no deadlock.
// Rationale: 6 rounds of bookkeeping show ~48us overhead PER DEPENDENT
// DISPATCH (2 launches = 106us fixed, 1 launch = 58us) -> fusing saves ~48us.
// ---------------------------------------------------------------------------
__global__ __launch_bounds__(1024) void fused_kernel(
    const float* __restrict__ loc, const float* __restrict__ conf,
    const float* __restrict__ dbox, const float* __restrict__ targets,
    float* __restrict__ ce0, unsigned char* __restrict__ pack,
    unsigned long long* __restrict__ keys,
    unsigned* __restrict__ res, unsigned* __restrict__ done,
    unsigned* __restrict__ done2, float* __restrict__ out) {
  const int tid = threadIdx.x;
  const int wb = tid >> 6, lane = tid & 63;
  const int b = blockIdx.x >> 1;
  const int cg = (blockIdx.x & 1) * 16 + wb;     // 0..31

  __shared__ SmemU u;
  __shared__ int s_do, s_fin;
  __shared__ unsigned s_prefix;
  __shared__ int s_kk, s_cnt, s_cc, s_np;
  __shared__ float s_floc, s_fcep;

  // ================= stream phase (R11 body, barrier-free per wave) ========
  for (int i = lane; i < On * 5; i += 64)
    u.st.tt[wb][i] = targets[(size_t)b * On * 5 + i];
  if (lane < On) {
    float x1 = targets[(size_t)b * On * 5 + lane * 5 + 0];
    float y1 = targets[(size_t)b * On * 5 + lane * 5 + 1];
    float x2 = targets[(size_t)b * On * 5 + lane * 5 + 2];
    float y2 = targets[(size_t)b * On * 5 + lane * 5 + 3];
    u.st.ar[wb][lane] = (x2 - x1) * (y2 - y1);
  }

  float bestv[On]; int bestp[On];
  #pragma unroll
  for (int j = 0; j < On; j++) { bestv[j] = -1.0f; bestp[j] = 0x7fffffff; }

  #pragma unroll
  for (int i = 0; i < 5; i++) {
    const int ci = cg + 32 * i;
    if (ci >= 137) break;
    const int p0 = ci * 64;
    const int rows = min(64, Pn - p0);           // 64 or 28
    const int n4 = rows * Cn / 4;                // 336 or 147

    const float4* src = (const float4*)(conf + ((size_t)b * Pn + p0) * Cn);
    float4 v0, v1, v2, v3, v4, v5;
    if (lane < n4)        v0 = src[lane];
    if (lane + 64 < n4)   v1 = src[lane + 64];
    if (lane + 128 < n4)  v2 = src[lane + 128];
    if (lane + 192 < n4)  v3 = src[lane + 192];
    if (lane + 256 < n4)  v4 = src[lane + 256];
    if (lane + 320 < n4)  v5 = src[lane + 320];
    if (lane < n4)        u.st.row4[wb][lane] = v0;
    if (lane + 64 < n4)   u.st.row4[wb][lane + 64] = v1;
    if (lane + 128 < n4)  u.st.row4[wb][lane + 128] = v2;
    if (lane + 192 < n4)  u.st.row4[wb][lane + 192] = v3;
    if (lane + 256 < n4)  u.st.row4[wb][lane + 256] = v4;
    if (lane + 320 < n4)  u.st.row4[wb][lane + 320] = v5;

    if (lane < rows) {
      const int p = p0 + lane;
      const float* x = (const float*)u.st.row4[wb] + lane * Cn;
      float g0 = fmaxf(fmaxf(x[0],  x[1]),  x[2]);
      float g1 = fmaxf(fmaxf(x[3],  x[4]),  x[5]);
      float g2 = fmaxf(fmaxf(x[6],  x[7]),  x[8]);
      float g3 = fmaxf(fmaxf(x[9],  x[10]), x[11]);
      float g4 = fmaxf(fmaxf(x[12], x[13]), x[14]);
      float g5 = fmaxf(fmaxf(x[15], x[16]), x[17]);
      float g6 = fmaxf(fmaxf(x[18], x[19]), x[20]);
      float m  = fmaxf(fmaxf(fmaxf(fmaxf(g0, g1), g2),
                             fmaxf(fmaxf(g3, g4), g5)), g6);
      float s0 = __expf(x[0] - m), s1 = __expf(x[1] - m);
      float s2 = __expf(x[2] - m), s3 = __expf(x[3] - m);
      #pragma unroll
      for (int q = 4; q < 20; q += 4) {
        s0 += __expf(x[q]     - m);
        s1 += __expf(x[q + 1] - m);
        s2 += __expf(x[q + 2] - m);
        s3 += __expf(x[q + 3] - m);
      }
      s0 += __expf(x[20] - m);
      float lse = m + __logf((s0 + s1) + (s2 + s3));
      ce0[(size_t)b * Pn + p] = lse - x[0];

      float4 d = ((const float4*)dbox)[p];
      float px1 = d.x - d.z * 0.5f, py1 = d.y - d.w * 0.5f;
      float px2 = d.x + d.z * 0.5f, py2 = d.y + d.w * 0.5f;
      float ap = d.z * d.w;
      float mv0 = -1.0f, mv1 = -1.0f; int mj0 = 0, mj1 = 8;
      #pragma unroll
      for (int j = 0; j < 8; j++) {
        float lx = fmaxf(u.st.tt[wb][j*5+0], px1);
        float ly = fmaxf(u.st.tt[wb][j*5+1], py1);
        float rx = fminf(u.st.tt[wb][j*5+2], px2);
        float ry = fminf(u.st.tt[wb][j*5+3], py2);
        float w = fmaxf(rx - lx, 0.0f), h = fmaxf(ry - ly, 0.0f);
        float inter = w * h;
        float ov = __fdividef(inter, u.st.ar[wb][j] + ap - inter);
        if (ov > bestv[j]) { bestv[j] = ov; bestp[j] = p; }
        if (ov > mv0) { mv0 = ov; mj0 = j; }
      }
      #pragma unroll
      for (int j = 8; j < On; j++) {
        float lx = fmaxf(u.st.tt[wb][j*5+0], px1);
        float ly = fmaxf(u.st.tt[wb][j*5+1], py1);
        float rx = fminf(u.st.tt[wb][j*5+2], px2);
        float ry = fminf(u.st.tt[wb][j*5+3], py2);
        float w = fmaxf(rx - lx, 0.0f), h = fmaxf(ry - ly, 0.0f);
        float inter = w * h;
        float ov = __fdividef(inter, u.st.ar[wb][j] + ap - inter);
        if (ov > bestv[j]) { bestv[j] = ov; bestp[j] = p; }
        if (ov > mv1) { mv1 = ov; mj1 = j; }
      }
      float mv; int mj;
      if (mv1 > mv0) { mv = mv1; mj = mj1; } else { mv = mv0; mj = mj0; }
      pack[(size_t)b * Pn + p] =
          (unsigned char)(mj | ((mv >= 0.5f) ? 16 : 0));
    }
  }

  #pragma unroll
  for (int j = 0; j < On; j++) {
    float v = bestv[j]; int p = bestp[j];
    #pragma unroll
    for (int off = 32; off; off >>= 1) {
      float v2 = __shfl_down(v, off);
      int p2 = __shfl_down(p, off);
      argmax_combine(v, p, v2, p2);
    }
    if (lane == 0) {
      unsigned long long key;
      if (v < 0.0f) key = 0xC000000000000000ull;   // neutral, beats poison
      else key = (((unsigned long long)(__float_as_uint(v) | 0xC0000000u)) << 32)
               | (unsigned long long)(0xFFFFFFFFu - (unsigned)p);
      atomicMax(&keys[b * On + j], key);
    }
  }

  // ================= handoff: last-arriving block of image b reduces =======
  __syncthreads();
  if (tid == 0) {
    __threadfence();                              // release ce0/pack/keys
    unsigned o = atomicAdd(&done[b], 1u);
    s_do = (o == 1u) ? 1 : 0;
  }
  __syncthreads();                                // also fences union st->rd
  if (!s_do) return;                              // first block exits; no spin
  __threadfence();                                // acquire partner's writes

  // ================= reduce phase (R9 1024-thread body) ====================
  if (tid < On * 5) u.rd.t[tid] = targets[(size_t)b * On * 5 + tid];
  if (tid < 273) u.rd.bm[tid] = 0;
  __syncthreads();
  if (tid < On) {
    int bp = (int)(0xFFFFFFFFu - (unsigned)(keys[b * On + tid] & 0xFFFFFFFFull));
    u.rd.bp[tid] = bp;
    atomicOr(&u.rd.bm[bp >> 5], 1u << (bp & 31));
  }
  __syncthreads();

  if (wb == 0) {                                  // forced-prior losses
    float f_loc = 0.f, f_cep = 0.f;
    const bool valid = lane < On;
    const int p = valid ? u.rd.bp[lane] : 0;
    bool dup = false;
    if (valid)
      for (int j2 = lane + 1; j2 < On; j2++) dup |= (u.rd.bp[j2] == p);
    if (valid && !dup) {                          // last j wins on collisions
      const float* row = conf + ((size_t)b * Pn + p) * Cn;
      float m = row[0];
      #pragma unroll
      for (int q = 1; q < Cn; q++) m = fmaxf(m, row[q]);
      float s = 0.f;
      #pragma unroll
      for (int q = 0; q < Cn; q++) s += __expf(row[q] - m);
      const float lse = m + __logf(s);
      const int c = (int)u.rd.t[lane * 5 + 4] + 1;
      f_cep = lse - row[c];
      const float4 d = ((const float4*)dbox)[p];
      const float4 lv = ((const float4*)loc)[(size_t)b * Pn + p];
      f_loc = sl1_enc(lv, d, u.rd.t[lane*5+0], u.rd.t[lane*5+1],
                             u.rd.t[lane*5+2], u.rd.t[lane*5+3]);
    }
    #pragma unroll
    for (int off = 32; off; off >>= 1) {
      f_loc += __shfl_down(f_loc, off);
      f_cep += __shfl_down(f_cep, off);
    }
    if (lane == 0) { s_floc = f_loc; s_fcep = f_cep; }
  }

  float ce_r[9];
  float my_loc = 0.0f, my_cep = 0.0f; int my_np = 0;
  #pragma unroll
  for (int sI = 0; sI < 9; sI++) {
    ce_r[sI] = 0.0f;
    const int p = tid + 1024 * sI;
    if (p < Pn) {
      unsigned char pk = pack[(size_t)b * Pn + p];
      float c0 = ce0[(size_t)b * Pn + p];
      const unsigned forced = (u.rd.bm[p >> 5] >> (p & 31)) & 1u;
      const int posb = (pk >> 4);
      const int pos = posb | (int)forced;
      ce_r[sI] = pos ? 0.0f : c0;
      if (pos) my_np++;
      if (posb && !forced) {
        const int bt = pk & 15;
        const float* t = &u.rd.t[bt * 5];
        int c = (int)t[4] + 1;
        const float* row = conf + ((size_t)b * Pn + p) * Cn;
        my_cep += c0 + row[0] - row[c];           // lse - x[c]
        float4 d = ((const float4*)dbox)[p];
        float4 ld = ((const float4*)loc)[(size_t)b * Pn + p];
        my_loc += sl1_enc(ld, d, t[0], t[1], t[2], t[3]);
      }
    }
  }

  {
    int np = my_np;
    #pragma unroll
    for (int off = 32; off; off >>= 1) np += __shfl_down(np, off);
    if (lane == 0) u.rd.redi[wb] = np;
  }
  __syncthreads();
  if (tid == 0) {
    int np = 0;
    #pragma unroll
    for (int w = 0; w < 16; w++) np += u.rd.redi[w];
    s_np = np;
  }
  __syncthreads();

  const int k = min(s_np * 3, Pn);
  unsigned prefix = 0, maskb = 0;
  int kk = k;
  int cntc = Pn;
  for (int shift = 24; shift >= 0; shift -= 8) {
    if (cntc <= 64) break;
    ((uint4*)u.rd.hist)[tid] = make_uint4(0u, 0u, 0u, 0u);
    __syncthreads();
    #pragma unroll
    for (int sI = 0; sI < 9; sI++) {
      const int p = tid + 1024 * sI;
      if (p < Pn) {
        unsigned uu = __float_as_uint(ce_r[sI]);
        if ((uu & maskb) == prefix)
          atomicAdd(&u.rd.hist[(((uu >> shift) & 255u) << 4) + (unsigned)wb], 1u);
      }
    }
    __syncthreads();
    if (tid < 256) {
      unsigned c = 0;
      #pragma unroll
      for (int w = 0; w < 16; w++) c += u.rd.hist[(tid << 4) + w];
      u.rd.col[tid] = c;
    }
    __syncthreads();
    if (tid < 64) {
      unsigned c0 = u.rd.col[4 * tid + 0], c1 = u.rd.col[4 * tid + 1];
      unsigned c2 = u.rd.col[4 * tid + 2], c3 = u.rd.col[4 * tid + 3];
      unsigned t0 = c0 + c1 + c2 + c3;
      unsigned S = t0;
      #pragma unroll
      for (int off = 1; off < 64; off <<= 1) {
        unsigned o = __shfl_down(S, off);
        if (tid + off < 64) S += o;
      }
      unsigned Snext = S - t0;
      unsigned s3 = Snext + c3;
      unsigned s2 = s3 + c2;
      unsigned s1 = s2 + c1;
      unsigned s0 = s1 + c0;
      unsigned kk_u = (unsigned)kk;
      int chosen = -1; unsigned snx = 0, cc = 0;
      if (s3 >= kk_u && Snext < kk_u)      { chosen = 3; snx = Snext; cc = c3; }
      else if (s2 >= kk_u && s3 < kk_u)    { chosen = 2; snx = s3;    cc = c2; }
      else if (s1 >= kk_u && s2 < kk_u)    { chosen = 1; snx = s2;    cc = c1; }
      else if (s0 >= kk_u && s1 < kk_u)    { chosen = 0; snx = s1;    cc = c0; }
      if (chosen >= 0) {
        s_prefix = prefix | ((unsigned)(4 * tid + chosen) << shift);
        s_kk = (int)(kk_u - snx);
        s_cnt = (int)cc;
      }
    }
    __syncthreads();
    prefix = s_prefix; kk = s_kk; cntc = s_cnt;
    maskb |= 255u << shift;
  }
  if (maskb != 0xFFFFFFFFu) {
    if (tid == 0) s_cc = 0;
    __syncthreads();
    #pragma unroll
    for (int sI = 0; sI < 9; sI++) {
      const int p = tid + 1024 * sI;
      if (p < Pn) {
        unsigned uu = __float_as_uint(ce_r[sI]);
        if ((uu & maskb) == prefix) {
          int ix = atomicAdd(&s_cc, 1);
          if (ix < 64) u.rd.cand[ix] = uu;
        }
      }
    }
    __syncthreads();
    if (tid < 64) {
      int c = min(s_cc, 64);
      if (tid < c) {
        unsigned v = u.rd.cand[tid];
        int g = 0, e = 0;
        for (int i = 0; i < c; i++) {
          unsigned w = u.rd.cand[i];
          g += (w > v); e += (w == v);
        }
        if (g < kk && kk <= g + e) s_prefix = v;
      }
    }
    __syncthreads();
    prefix = s_prefix;
  }
  float T = __uint_as_float(prefix);

  float sum_gt = 0.0f; int cnt_gt = 0;
  #pragma unroll
  for (int sI = 0; sI < 9; sI++) {
    const int p = tid + 1024 * sI;
    if (p < Pn) {
      float x = ce_r[sI];
      if (x > T) { sum_gt += x; cnt_gt++; }
    }
  }
  #pragma unroll
  for (int off = 32; off; off >>= 1) {
    sum_gt += __shfl_down(sum_gt, off);
    cnt_gt += __shfl_down(cnt_gt, off);
    my_loc += __shfl_down(my_loc, off);
    my_cep += __shfl_down(my_cep, off);
  }
  if (lane == 0) {
    u.rd.redf[0][wb] = my_loc;
    u.rd.redf[1][wb] = sum_gt + my_cep;
    u.rd.redi[wb] = cnt_gt;
  }
  __syncthreads();
  if (tid == 0) {
    float ll = s_floc, lc = s_fcep; int cg2 = 0;
    #pragma unroll
    for (int w = 0; w < 16; w++) {
      ll += u.rd.redf[0][w]; lc += u.rd.redf[1][w]; cg2 += u.rd.redi[w];
    }
    lc += (k > 0) ? (float)(k - cg2) * T : 0.0f;
    atomicExch(&res[b * 4 + 0], __float_as_uint(ll));
    atomicExch(&res[b * 4 + 1], __float_as_uint(lc));
    atomicExch(&res[b * 4 + 2], (unsigned)s_np);
    __threadfence();                              // release partials
    unsigned o2 = atomicAdd(done2, 1u);
    s_fin = (o2 == (unsigned)(Bn - 1)) ? 1 : 0;   // 128th reducer finalizes
  }
  __syncthreads();

  // ================= finalize (spin-free: all partials posted) =============
  if (s_fin) {
    __threadfence();                              // acquire all partials
    float ll = 0.0f, lc = 0.0f; int np = 0;
    if (tid < Bn) {
      ll = __uint_as_float(atomicAdd(&res[tid * 4 + 0], 0u));
      lc = __uint_as_float(atomicAdd(&res[tid * 4 + 1], 0u));
      np = (int)atomicAdd(&res[tid * 4 + 2], 0u);
    }
    #pragma unroll
    for (int off = 32; off; off >>= 1) {
      ll += __shfl_down(ll, off);
      lc += __shfl_down(lc, off);
      np += __shfl_down(np, off);
    }
    if (lane == 0 && wb < 2) {
      u.rd.redf[0][wb] = ll; u.rd.redf[1][wb] = lc; u.rd.redi[wb] = np;
    }
    __syncthreads();
    if (tid == 0) {
      float L = u.rd.redf[0][0] + u.rd.redf[0][1];
      float C = u.rd.redf[1][0] + u.rd.redf[1][1];
      float N = (float)(u.rd.redi[0] + u.rd.redi[1]);
      out[0] = L / N;
      out[1] = C / N;
    }
  }
}

extern "C" void kernel_launch(void* const* d_in, const int* in_sizes, int n_in,
                              void* d_out, int out_size, void* d_ws, size_t ws_size,
                              hipStream_t stream) {
  const float* loc_data  = (const float*)d_in[0];
  const float* conf_data = (const float*)d_in[1];
  const float* dbox      = (const float*)d_in[2];
  const float* targets   = (const float*)d_in[3];
  float* out = (float*)d_out;

  char* ws = (char*)d_ws;
  float* ce0 = (float*)ws;                                           // B*P f32
  unsigned char* pack = (unsigned char*)(ws + (size_t)Bn * Pn * 4);  // B*P bytes
  unsigned long long* keys =
      (unsigned long long*)(ws + (size_t)Bn * Pn * 5);               // B*16 u64
  unsigned int* res =
      (unsigned int*)(ws + (size_t)Bn * Pn * 5 + (size_t)Bn * On * 8); // B*4 u32
  unsigned int* done  = res + Bn * 4;                                // B u32
  unsigned int* done2 = done + Bn;                                   // 1 u32

  // zero the completion counters only (keys/res are poison-robust)
  hipMemsetAsync(done, 0, (size_t)(Bn + 1) * sizeof(unsigned), stream);

  fused_kernel<<<2 * Bn, 1024, 0, stream>>>(
      loc_data, conf_data, dbox, targets, ce0, pack, keys, res, done, done2, out);
}